// Round 3
// baseline (715.690 us; speedup 1.0000x reference)
//
#include <hip/hip_runtime.h>
#include <math.h>

// Problem constants
#define BATCH 262144

// ws layout (float offsets)
#define G6_OFF  18432    // [8][8]  C^T diag(1/(R+1e-6)) C
#define G8_OFF  18496    // [8][8]  C^T diag(1/(R+1e-8)) C
#define R6_OFF  18560    // [16] 1/(R+1e-6)
#define R8_OFF  18576    // [16] 1/(R+1e-8)
#define SLR_OFF 18592    // scalar: sum log(R+1e-6)

__device__ __forceinline__ float rcp1(float x) {
    float r = __builtin_amdgcn_rcpf(x);
    return r * (2.0f - x * r);   // one Newton step: ~1e-7 rel err
}
__device__ __forceinline__ float sigm(float x) {
    float e = __expf(-fabsf(x));          // in (0,1], never overflows
    float s = rcp1(1.0f + e);             // sigm(|x|)
    return (x >= 0.0f) ? s : e * s;       // sigm(-|x|) = e*s
}
__device__ __forceinline__ float tanh_f(float x) {
    float e = __expf(-2.0f * fabsf(x));   // in (0,1]
    float t = (1.0f - e) * rcp1(1.0f + e);
    return copysignf(t, x);
}

// ---------------- prep: batch-independent stats for the tail -----------------
__global__ void prep_kernel(const float* __restrict__ Cm,   // [16][8]
                            const float* __restrict__ logR, // [16]
                            float* __restrict__ ws) {
    int t = threadIdx.x;
    if (t < 64) {
        int k = t >> 3, l = t & 7;
        float g6 = 0.0f, g8 = 0.0f;
        for (int i = 0; i < 16; ++i) {
            float R  = expf(logR[i]);
            float cc = Cm[i * 8 + k] * Cm[i * 8 + l];
            g6 += cc / (R + 1e-6f);
            g8 += cc / (R + 1e-8f);
        }
        ws[G6_OFF + t] = g6;
        ws[G8_OFF + t] = g8;
    } else if (t < 80) {
        int i = t - 64;
        float R = expf(logR[i]);
        ws[R6_OFF + i] = 1.0f / (R + 1e-6f);
        ws[R8_OFF + i] = 1.0f / (R + 1e-8f);
    } else if (t == 80) {
        float s = 0.0f;
        for (int i = 0; i < 16; ++i) s += logf(expf(logR[i]) + 1e-6f);
        ws[SLR_OFF] = s;
    }
}

// ---------------- LSTM kernel: weights in VGPRs, 1 wave = 64 elements --------
// Lane l owns unit l. wI/wF/wG/wO[72] hold the 4 gate weight columns for that
// unit in registers (preloaded once, reused for all 64 elements). ha[e][k] is
// wave-uniform per element -> LDS broadcast reads. No barriers in main loop.
__global__ __launch_bounds__(64, 1)
void lstm_kernel(const float* __restrict__ h_in,
                 const float* __restrict__ c_in,
                 const float* __restrict__ z_prev,
                 const float* __restrict__ Wk,     // [8][256]
                 const float* __restrict__ Wr,     // [64][256]
                 const float* __restrict__ b_lstm, // [256]
                 float* __restrict__ out) {
    __shared__ __align__(16) float ha_w[64 * 76];  // [e][76]: 0..7 z, 8..71 h (later h_new at 8+u)
    __shared__ __align__(16) float c_w[64 * 64];   // [e][u]  c_old, overwritten by c_new

    const int l = threadIdx.x;                     // lane = unit
    const size_t E0 = (size_t)blockIdx.x * 64;

    // ---- weight preload into 288 VGPRs (coalesced: consecutive lanes, consecutive cols)
    float wI[72], wF[72], wG[72], wO[72];
#pragma unroll
    for (int k = 0; k < 8; ++k) {
        wI[k] = Wk[k * 256 + l];
        wF[k] = Wk[k * 256 + 64 + l];
        wG[k] = Wk[k * 256 + 128 + l];
        wO[k] = Wk[k * 256 + 192 + l];
    }
#pragma unroll
    for (int k = 0; k < 64; ++k) {
        wI[8 + k] = Wr[k * 256 + l];
        wF[8 + k] = Wr[k * 256 + 64 + l];
        wG[8 + k] = Wr[k * 256 + 128 + l];
        wO[8 + k] = Wr[k * 256 + 192 + l];
    }
    const float bi = b_lstm[l], bf = b_lstm[64 + l], bg = b_lstm[128 + l], bo = b_lstm[192 + l];

    // ---- stage z (fully linear global reads) ----
#pragma unroll
    for (int i = 0; i < 2; ++i) {
        int idx = i * 64 + l; int e = idx >> 1, p = idx & 1;
        float4 v = *(const float4*)(z_prev + E0 * 8 + (size_t)idx * 4);
        *(float4*)(ha_w + e * 76 + p * 4) = v;
    }
    // ---- stage h, c ----
#pragma unroll
    for (int i = 0; i < 16; ++i) {
        int idx = i * 64 + l; int e = idx >> 4, q = idx & 15;
        float4 hv = *(const float4*)(h_in + E0 * 64 + (size_t)idx * 4);
        float4 cv = *(const float4*)(c_in + E0 * 64 + (size_t)idx * 4);
        *(float4*)(ha_w + e * 76 + 8 + q * 4) = hv;
        *(float4*)(c_w + e * 64 + q * 4) = cv;
    }
    __syncthreads();   // single wave: just orders LDS writes vs reads

    // ---- main loop: 2 elements per iteration, 8 acc chains ----
#pragma unroll 1
    for (int e0 = 0; e0 < 64; e0 += 2) {
        const float4* A = (const float4*)(ha_w + e0 * 76);
        const float4* B = (const float4*)(ha_w + (e0 + 1) * 76);
        float zi0 = bi, zf0 = bf, zg0 = bg, zo0 = bo;
        float zi1 = bi, zf1 = bf, zg1 = bg, zo1 = bo;
#pragma unroll
        for (int kq = 0; kq < 18; ++kq) {
            float4 a = A[kq], b = B[kq];
            zi0 = fmaf(a.x, wI[4 * kq + 0], zi0);
            zf0 = fmaf(a.x, wF[4 * kq + 0], zf0);
            zg0 = fmaf(a.x, wG[4 * kq + 0], zg0);
            zo0 = fmaf(a.x, wO[4 * kq + 0], zo0);
            zi1 = fmaf(b.x, wI[4 * kq + 0], zi1);
            zf1 = fmaf(b.x, wF[4 * kq + 0], zf1);
            zg1 = fmaf(b.x, wG[4 * kq + 0], zg1);
            zo1 = fmaf(b.x, wO[4 * kq + 0], zo1);
            zi0 = fmaf(a.y, wI[4 * kq + 1], zi0);
            zf0 = fmaf(a.y, wF[4 * kq + 1], zf0);
            zg0 = fmaf(a.y, wG[4 * kq + 1], zg0);
            zo0 = fmaf(a.y, wO[4 * kq + 1], zo0);
            zi1 = fmaf(b.y, wI[4 * kq + 1], zi1);
            zf1 = fmaf(b.y, wF[4 * kq + 1], zf1);
            zg1 = fmaf(b.y, wG[4 * kq + 1], zg1);
            zo1 = fmaf(b.y, wO[4 * kq + 1], zo1);
            zi0 = fmaf(a.z, wI[4 * kq + 2], zi0);
            zf0 = fmaf(a.z, wF[4 * kq + 2], zf0);
            zg0 = fmaf(a.z, wG[4 * kq + 2], zg0);
            zo0 = fmaf(a.z, wO[4 * kq + 2], zo0);
            zi1 = fmaf(b.z, wI[4 * kq + 2], zi1);
            zf1 = fmaf(b.z, wF[4 * kq + 2], zf1);
            zg1 = fmaf(b.z, wG[4 * kq + 2], zg1);
            zo1 = fmaf(b.z, wO[4 * kq + 2], zo1);
            zi0 = fmaf(a.w, wI[4 * kq + 3], zi0);
            zf0 = fmaf(a.w, wF[4 * kq + 3], zf0);
            zg0 = fmaf(a.w, wG[4 * kq + 3], zg0);
            zo0 = fmaf(a.w, wO[4 * kq + 3], zo0);
            zi1 = fmaf(b.w, wI[4 * kq + 3], zi1);
            zf1 = fmaf(b.w, wF[4 * kq + 3], zf1);
            zg1 = fmaf(b.w, wG[4 * kq + 3], zg1);
            zo1 = fmaf(b.w, wO[4 * kq + 3], zo1);
        }
        float c0 = c_w[e0 * 64 + l];
        float c1 = c_w[(e0 + 1) * 64 + l];
        float cn0 = sigm(zf0) * c0 + sigm(zi0) * tanh_f(zg0);
        float hn0 = sigm(zo0) * tanh_f(cn0);
        float cn1 = sigm(zf1) * c1 + sigm(zi1) * tanh_f(zg1);
        float hn1 = sigm(zo1) * tanh_f(cn1);
        ha_w[e0 * 76 + 8 + l]       = hn0;   // overwrite consumed h slot
        ha_w[(e0 + 1) * 76 + 8 + l] = hn1;
        c_w[e0 * 64 + l]       = cn0;
        c_w[(e0 + 1) * 64 + l] = cn1;
    }
    __syncthreads();

    // ---- coalesced write-out ----
    float* outH = out + (size_t)BATCH * 73  + E0 * 64;
    float* outC = out + (size_t)BATCH * 137 + E0 * 64;
#pragma unroll
    for (int i = 0; i < 16; ++i) {
        int idx = i * 64 + l; int e = idx >> 4, q = idx & 15;
        float4 hv = *(const float4*)(ha_w + e * 76 + 8 + q * 4);
        float4 cv = *(const float4*)(c_w + e * 64 + q * 4);
        *(float4*)(outH + (size_t)idx * 4) = hv;
        *(float4*)(outC + (size_t)idx * 4) = cv;
    }
}

// ---------------- tail kernel: mu/lsg GEMM + Gaussian tail -------------------
__global__ __launch_bounds__(256)
void tail_kernel(const float* __restrict__ x_in,
                 const float* __restrict__ W_mu,
                 const float* __restrict__ b_mu,
                 const float* __restrict__ W_ls,
                 const float* __restrict__ b_ls,
                 const float* __restrict__ Cm,
                 const float* __restrict__ b_em,
                 const float* __restrict__ ws,
                 float* __restrict__ out) {
    __shared__ float hn[64 * 65];     // [u][e] h_new tile; reused as V chunk buffer
    __shared__ float muls[16 * 257];  // [d][e256]

    const int t    = threadIdx.x;
    const int lane = t & 63;
    const int wv   = t >> 6;
    const int wvu  = __builtin_amdgcn_readfirstlane(wv);
    const int blk  = blockIdx.x;
    const float* hN = out + (size_t)BATCH * 73;

    for (int tile = 0; tile < 4; ++tile) {
        const size_t E0 = (size_t)blk * 256 + (size_t)tile * 64;
        // stage h_new transposed
#pragma unroll
        for (int i = 0; i < 4; ++i) {
            int g = i * 1024 + t * 4;
            int e = g >> 6, u = g & 63;
            float4 hv = *(const float4*)(hN + E0 * 64 + g);
            hn[(u + 0) * 65 + e] = hv.x;
            hn[(u + 1) * 65 + e] = hv.y;
            hn[(u + 2) * 65 + e] = hv.z;
            hn[(u + 3) * 65 + e] = hv.w;
        }
        __syncthreads();
        // mu / log_sigma: thread = (elem lane, d-pair wvu)
        {
            int d0 = wvu * 2;
            float m0 = b_mu[d0], m1 = b_mu[d0 + 1];
            float l0 = b_ls[d0], l1 = b_ls[d0 + 1];
#pragma unroll
            for (int u = 0; u < 64; ++u) {
                float hv = hn[u * 65 + lane];
                m0 = fmaf(hv, W_mu[u * 8 + d0],     m0);
                m1 = fmaf(hv, W_mu[u * 8 + d0 + 1], m1);
                l0 = fmaf(hv, W_ls[u * 8 + d0],     l0);
                l1 = fmaf(hv, W_ls[u * 8 + d0 + 1], l1);
            }
            int col = tile * 64 + lane;
            muls[(d0 + 0) * 257 + col] = m0;
            muls[(d0 + 1) * 257 + col] = m1;
            muls[(8 + d0 + 0) * 257 + col] = l0;
            muls[(8 + d0 + 1) * 257 + col] = l1;
        }
        __syncthreads();   // before next tile overwrites hn
    }

    // ---- per-element tail: element = blk*256 + t ----
    const float* G6 = ws + G6_OFF;
    const float* G8 = ws + G8_OFF;
    const float* r6 = ws + R6_OFF;
    const float* r8 = ws + R8_OFF;
    const float  slr = ws[SLR_OFF];
    const size_t e = (size_t)blk * 256 + t;

    float mu[8], lsg[8];
#pragma unroll
    for (int d = 0; d < 8; ++d) {
        mu[d]  = muls[d * 257 + t];
        lsg[d] = muls[(8 + d) * 257 + t];
    }

    float sig[8], Sinv[8];
#pragma unroll
    for (int d = 0; d < 8; ++d) {
        float l = fminf(fmaxf(lsg[d], -5.0f), 3.0f);
        float s = __expf(l);
        sig[d]  = s;
        Sinv[d] = rcp1(s * s + 1e-8f);
    }

    float xv[16];
    {
        const float4* x4 = (const float4*)(x_in + e * 16);
#pragma unroll
        for (int q = 0; q < 4; ++q) {
            float4 v = x4[q];
            xv[4 * q + 0] = v.x; xv[4 * q + 1] = v.y;
            xv[4 * q + 2] = v.z; xv[4 * q + 3] = v.w;
        }
    }

    float t6[8], t8[8];
#pragma unroll
    for (int k = 0; k < 8; ++k) { t6[k] = 0.0f; t8[k] = 0.0f; }
    float qdr = 0.0f;
#pragma unroll
    for (int i = 0; i < 16; ++i) {
        float pm = b_em[i];
#pragma unroll
        for (int d = 0; d < 8; ++d) pm = fmaf(mu[d], Cm[i * 8 + d], pm);
        float df = xv[i] - pm;
        float xe = xv[i] - b_em[i];
        float a6 = df * r6[i];
        float a8 = xe * r8[i];
        qdr = fmaf(df, a6, qdr);
#pragma unroll
        for (int k = 0; k < 8; ++k) {
            t6[k] = fmaf(a6, Cm[i * 8 + k], t6[k]);
            t8[k] = fmaf(a8, Cm[i * 8 + k], t8[k]);
        }
    }

    // ---- alpha via Woodbury ----
    float M[8][8];
#pragma unroll
    for (int k = 0; k < 8; ++k)
#pragma unroll
        for (int l = 0; l <= k; ++l)
            M[k][l] = ((k == l) ? 1.0f : 0.0f) + sig[k] * sig[l] * G6[k * 8 + l];

    float ldia[8];
    float logdetM = 0.0f;
#pragma unroll
    for (int k = 0; k < 8; ++k) {
        float d = M[k][k];
#pragma unroll
        for (int j = 0; j < k; ++j) d = fmaf(-M[k][j], M[k][j], d);
        float l = sqrtf(d);
        logdetM += __logf(d);
        float li = rcp1(l);
        M[k][k] = l; ldia[k] = li;
#pragma unroll
        for (int i = k + 1; i < 8; ++i) {
            float s = M[i][k];
#pragma unroll
            for (int j = 0; j < k; ++j) s = fmaf(-M[i][j], M[k][j], s);
            M[i][k] = s * li;
        }
    }
    float w[8];
    float ssq = 0.0f;
#pragma unroll
    for (int k = 0; k < 8; ++k) {
        float s = sig[k] * t6[k];
#pragma unroll
        for (int j = 0; j < k; ++j) s = fmaf(-M[k][j], w[j], s);
        w[k] = s * ldia[k];
        ssq  = fmaf(w[k], w[k], ssq);
    }
    float mahal  = qdr - ssq;
    float logdet = slr + logdetM;
    float alpha  = -0.5f * (mahal + logdet + 29.40603306254952f); // 16*ln(2pi)

    // ---- gamma: V = (diag(Sinv)+1e-6 I + G8)^-1 ----
    float Vi[8][8];
#pragma unroll
    for (int k = 0; k < 8; ++k)
#pragma unroll
        for (int l = 0; l <= k; ++l)
            Vi[k][l] = G8[k * 8 + l] + ((k == l) ? (Sinv[k] + 1e-6f) : 0.0f);

    float vdia[8];
#pragma unroll
    for (int k = 0; k < 8; ++k) {
        float d = Vi[k][k];
#pragma unroll
        for (int j = 0; j < k; ++j) d = fmaf(-Vi[k][j], Vi[k][j], d);
        float l = sqrtf(d);
        float li = rcp1(l);
        Vi[k][k] = l; vdia[k] = li;
#pragma unroll
        for (int i = k + 1; i < 8; ++i) {
            float s = Vi[i][k];
#pragma unroll
            for (int j = 0; j < k; ++j) s = fmaf(-Vi[i][j], Vi[k][j], s);
            Vi[i][k] = s * li;
        }
    }
    // J = L^-1 (lower), stored into M (dead)
#pragma unroll
    for (int k = 0; k < 8; ++k) {
        M[k][k] = vdia[k];
#pragma unroll
        for (int i = k + 1; i < 8; ++i) {
            float s = 0.0f;
#pragma unroll
            for (int j = k; j < i; ++j) s = fmaf(Vi[i][j], M[j][k], s);
            M[i][k] = -s * vdia[i];
        }
    }
    float info[8];
#pragma unroll
    for (int k = 0; k < 8; ++k) info[k] = fmaf(Sinv[k], mu[k], t8[k]);

    // ---- V = J^T J + gamma, staged through LDS (reuse hn) in 4 chunks ----
    __syncthreads();
#pragma unroll 1
    for (int ch = 0; ch < 4; ++ch) {
        if (wv == ch) {
            float gam[8];
#pragma unroll
            for (int a = 0; a < 8; ++a) gam[a] = 0.0f;
#pragma unroll
            for (int a = 0; a < 8; ++a) {
#pragma unroll
                for (int b = 0; b < 8; ++b) {
                    int m0 = (a > b) ? a : b;
                    float s = 0.0f;
#pragma unroll
                    for (int i = 0; i < 8; ++i)
                        if (i >= m0) s = fmaf(M[i][a], M[i][b], s);
                    hn[(a * 8 + b) * 65 + lane] = s;
                    gam[a] = fmaf(s, info[b], gam[a]);
                }
            }
            out[e] = alpha;
            float4* outG = (float4*)(out + (size_t)BATCH + e * 8);
            outG[0] = make_float4(gam[0], gam[1], gam[2], gam[3]);
            outG[1] = make_float4(gam[4], gam[5], gam[6], gam[7]);
        }
        __syncthreads();
        {
            float* outV = out + (size_t)BATCH * 9 + ((size_t)blk * 256 + (size_t)ch * 64) * 64;
#pragma unroll
            for (int i = 0; i < 4; ++i) {
                int g = i * 1024 + t * 4;
                int ee = g >> 6, j = g & 63;
                float4 v = make_float4(hn[(j + 0) * 65 + ee], hn[(j + 1) * 65 + ee],
                                       hn[(j + 2) * 65 + ee], hn[(j + 3) * 65 + ee]);
                *(float4*)(outV + g) = v;
            }
        }
        __syncthreads();
    }
}

extern "C" void kernel_launch(void* const* d_in, const int* in_sizes, int n_in,
                              void* d_out, int out_size, void* d_ws, size_t ws_size,
                              hipStream_t stream) {
    const float* h    = (const float*)d_in[0];
    const float* c    = (const float*)d_in[1];
    const float* zp   = (const float*)d_in[2];
    const float* xt   = (const float*)d_in[3];
    const float* Wk   = (const float*)d_in[4];
    const float* Wr   = (const float*)d_in[5];
    const float* bl   = (const float*)d_in[6];
    const float* Wmu  = (const float*)d_in[7];
    const float* bmu  = (const float*)d_in[8];
    const float* Wls  = (const float*)d_in[9];
    const float* bls  = (const float*)d_in[10];
    const float* Cm   = (const float*)d_in[11];
    const float* bem  = (const float*)d_in[12];
    const float* logR = (const float*)d_in[13];
    float* ws  = (float*)d_ws;
    float* out = (float*)d_out;

    hipLaunchKernelGGL(prep_kernel, dim3(1), dim3(256), 0, stream, Cm, logR, ws);
    hipLaunchKernelGGL(lstm_kernel, dim3(BATCH / 64), dim3(64), 0, stream,
                       h, c, zp, Wk, Wr, bl, out);
    hipLaunchKernelGGL(tail_kernel, dim3(BATCH / 256), dim3(256), 0, stream,
                       xt, Wmu, bmu, Wls, bls, Cm, bem, ws, out);
}

// Round 4
// 222.359 us; speedup vs baseline: 3.2186x; 3.2186x over previous
//
#include <hip/hip_runtime.h>
#include <math.h>

// Problem constants
#define BATCH 262144

// ws layout (float offsets)
#define WF_OFF  0        // [72][256] gate-interleaved fused weights: W_fused[k][u*4+g]
#define BF_OFF  18432    // [256] gate-interleaved bias b_fused[u*4+g]
#define G6_OFF  18944    // [8][8]  C^T diag(1/(R+1e-6)) C
#define G8_OFF  19008    // [8][8]  C^T diag(1/(R+1e-8)) C
#define R6_OFF  19072    // [16] 1/(R+1e-6)
#define R8_OFF  19088    // [16] 1/(R+1e-8)
#define SLR_OFF 19104    // scalar: sum log(R+1e-6)

__device__ __forceinline__ float rcp1(float x) {
    float r = __builtin_amdgcn_rcpf(x);
    return r * (2.0f - x * r);   // one Newton step: ~1e-7 rel err
}
__device__ __forceinline__ float sigm(float x) {
    float e = __expf(-fabsf(x));          // in (0,1], never overflows
    float s = rcp1(1.0f + e);             // sigm(|x|)
    return (x >= 0.0f) ? s : e * s;       // sigm(-|x|) = e*s
}
__device__ __forceinline__ float tanh_f(float x) {
    float e = __expf(-2.0f * fabsf(x));   // in (0,1]
    float t = (1.0f - e) * rcp1(1.0f + e);
    return copysignf(t, x);
}

// ---------------- prep: fuse/permute weights + batch-independent stats -------
__global__ void prep_kernel(const float* __restrict__ Wk,   // [8][256]
                            const float* __restrict__ Wr,   // [64][256]
                            const float* __restrict__ b_lstm,// [256]
                            const float* __restrict__ Cm,   // [16][8]
                            const float* __restrict__ logR, // [16]
                            float* __restrict__ ws) {
    int t = threadIdx.x;   // 0..255 = fused column c = u*4 + g
    int src = (t & 3) * 64 + (t >> 2);   // original column g*64+u
#pragma unroll
    for (int k = 0; k < 8; ++k)  ws[WF_OFF + k * 256 + t]       = Wk[k * 256 + src];
#pragma unroll
    for (int k = 0; k < 64; ++k) ws[WF_OFF + (8 + k) * 256 + t] = Wr[k * 256 + src];
    ws[BF_OFF + t] = b_lstm[src];

    if (t < 64) {
        int k = t >> 3, l = t & 7;
        float g6 = 0.0f, g8 = 0.0f;
        for (int i = 0; i < 16; ++i) {
            float R  = expf(logR[i]);
            float cc = Cm[i * 8 + k] * Cm[i * 8 + l];
            g6 += cc / (R + 1e-6f);
            g8 += cc / (R + 1e-8f);
        }
        ws[G6_OFF + t] = g6;
        ws[G8_OFF + t] = g8;
    } else if (t < 80) {
        int i = t - 64;
        float R = expf(logR[i]);
        ws[R6_OFF + i] = 1.0f / (R + 1e-6f);
        ws[R8_OFF + i] = 1.0f / (R + 1e-8f);
    } else if (t == 80) {
        float s = 0.0f;
        for (int i = 0; i < 16; ++i) s += logf(expf(logR[i]) + 1e-6f);
        ws[SLR_OFF] = s;
    }
}

// ---------------- LSTM kernel: register-tiled GEMM, weights via LDS ----------
// Block = 256 threads, tile = 64 elements x 256 gate-cols, per-thread 8x8.
// mt = t>>5 (elem group), nt = t&31 (col group: units 2nt,2nt+1 x 4 gates).
__global__ __launch_bounds__(256)
void lstm_kernel(const float* __restrict__ h_in,
                 const float* __restrict__ c_in,
                 const float* __restrict__ z_prev,
                 const float* __restrict__ ws,
                 float* __restrict__ out) {
    __shared__ __align__(16) float ha_lds[72 * 68];  // [k][e] z rows 0-7, h rows 8-71; later h_new[64][68]
    __shared__ __align__(16) float w_lds[24 * 256];  // K-chunk of W_fused; later c[64][68]

    const int t  = threadIdx.x;
    const int mt = t >> 5;     // 0..7
    const int nt = t & 31;     // 0..31
    const size_t E0 = (size_t)blockIdx.x * 64;
    const float* WF = ws + WF_OFF;

    // ---- stage ha (coalesced global -> LDS transpose) ----
#pragma unroll
    for (int i = 0; i < 4; ++i) {
        int g = i * 1024 + t * 4;      // 0..4095
        int e = g >> 6, u = g & 63;
        float4 hv = *(const float4*)(h_in + E0 * 64 + g);
        ha_lds[(8 + u + 0) * 68 + e] = hv.x;
        ha_lds[(8 + u + 1) * 68 + e] = hv.y;
        ha_lds[(8 + u + 2) * 68 + e] = hv.z;
        ha_lds[(8 + u + 3) * 68 + e] = hv.w;
    }
    if (t < 128) {
        int g = t * 4;                 // 0..511
        int e = g >> 3, d = g & 7;
        float4 zv = *(const float4*)(z_prev + E0 * 8 + g);
        ha_lds[(d + 0) * 68 + e] = zv.x;
        ha_lds[(d + 1) * 68 + e] = zv.y;
        ha_lds[(d + 2) * 68 + e] = zv.z;
        ha_lds[(d + 3) * 68 + e] = zv.w;
    }

    float acc[8][8];
#pragma unroll
    for (int j = 0; j < 8; ++j)
#pragma unroll
        for (int c = 0; c < 8; ++c) acc[j][c] = 0.0f;

    // ---- GEMM over K in 3 chunks of 24 ----
#pragma unroll 1
    for (int ch = 0; ch < 3; ++ch) {
        __syncthreads();   // ha staged (ch 0) / previous chunk FMAs done
#pragma unroll
        for (int i = 0; i < 6; ++i) {
            int off = (i * 256 + t) * 4;
            *(float4*)(w_lds + off) = *(const float4*)(WF + ch * (24 * 256) + off);
        }
        __syncthreads();
#pragma unroll 4
        for (int kk = 0; kk < 24; ++kk) {
            int k = ch * 24 + kk;
            float4 a0 = *(const float4*)(ha_lds + k * 68 + mt * 8);
            float4 a1 = *(const float4*)(ha_lds + k * 68 + mt * 8 + 4);
            float4 b0 = *(const float4*)(w_lds + kk * 256 + nt * 8);
            float4 b1 = *(const float4*)(w_lds + kk * 256 + nt * 8 + 4);
            float av[8] = {a0.x, a0.y, a0.z, a0.w, a1.x, a1.y, a1.z, a1.w};
            float bv[8] = {b0.x, b0.y, b0.z, b0.w, b1.x, b1.y, b1.z, b1.w};
#pragma unroll
            for (int j = 0; j < 8; ++j)
#pragma unroll
                for (int c = 0; c < 8; ++c)
                    acc[j][c] = fmaf(av[j], bv[c], acc[j][c]);
        }
    }
    __syncthreads();   // FMAs done; w_lds free for c staging

    // ---- stage c_old transposed into w_lds region: cT[u][68+e] ----
    float* cT = w_lds;           // [64][68] = 4352 floats <= 6144
    float* hL = ha_lds;          // reuse as h_new [64][68]
#pragma unroll
    for (int i = 0; i < 4; ++i) {
        int g = i * 1024 + t * 4;
        int e = g >> 6, u = g & 63;
        float4 cv = *(const float4*)(c_in + E0 * 64 + g);
        cT[(u + 0) * 68 + e] = cv.x;
        cT[(u + 1) * 68 + e] = cv.y;
        cT[(u + 2) * 68 + e] = cv.z;
        cT[(u + 3) * 68 + e] = cv.w;
    }
    __syncthreads();

    // ---- nonlinearity in-register: thread owns units 2nt,2nt+1, elems mt*8..+7 ----
    const float* BF = ws + BF_OFF;
#pragma unroll
    for (int un = 0; un < 2; ++un) {
        int u = 2 * nt + un;
        float bi = BF[u * 4 + 0], bf_ = BF[u * 4 + 1], bg = BF[u * 4 + 2], bo = BF[u * 4 + 3];
#pragma unroll
        for (int j = 0; j < 8; ++j) {
            int e = mt * 8 + j;
            float zi = acc[j][un * 4 + 0] + bi;
            float zf = acc[j][un * 4 + 1] + bf_;
            float zg = acc[j][un * 4 + 2] + bg;
            float zo = acc[j][un * 4 + 3] + bo;
            float cold = cT[u * 68 + e];
            float cn = sigm(zf) * cold + sigm(zi) * tanh_f(zg);
            float hn = sigm(zo) * tanh_f(cn);
            cT[u * 68 + e] = cn;
            hL[u * 68 + e] = hn;
        }
    }
    __syncthreads();

    // ---- coalesced write-out ----
    float* outH = out + (size_t)BATCH * 73  + E0 * 64;
    float* outC = out + (size_t)BATCH * 137 + E0 * 64;
#pragma unroll
    for (int i = 0; i < 4; ++i) {
        int g = i * 1024 + t * 4;
        int e = g >> 6, u = g & 63;
        float4 hv = make_float4(hL[(u + 0) * 68 + e], hL[(u + 1) * 68 + e],
                                hL[(u + 2) * 68 + e], hL[(u + 3) * 68 + e]);
        float4 cv = make_float4(cT[(u + 0) * 68 + e], cT[(u + 1) * 68 + e],
                                cT[(u + 2) * 68 + e], cT[(u + 3) * 68 + e]);
        *(float4*)(outH + g) = hv;
        *(float4*)(outC + g) = cv;
    }
}

// ---------------- tail kernel: mu/lsg GEMM + Gaussian tail -------------------
__global__ __launch_bounds__(256)
void tail_kernel(const float* __restrict__ x_in,
                 const float* __restrict__ W_mu,
                 const float* __restrict__ b_mu,
                 const float* __restrict__ W_ls,
                 const float* __restrict__ b_ls,
                 const float* __restrict__ Cm,
                 const float* __restrict__ b_em,
                 const float* __restrict__ ws,
                 float* __restrict__ out) {
    __shared__ float hn[64 * 65];     // [u][e] h_new tile; reused as V chunk buffer
    __shared__ float muls[16 * 257];  // [d][e256]

    const int t    = threadIdx.x;
    const int lane = t & 63;
    const int wv   = t >> 6;
    const int wvu  = __builtin_amdgcn_readfirstlane(wv);
    const int blk  = blockIdx.x;
    const float* hN = out + (size_t)BATCH * 73;

    for (int tile = 0; tile < 4; ++tile) {
        const size_t E0 = (size_t)blk * 256 + (size_t)tile * 64;
#pragma unroll
        for (int i = 0; i < 4; ++i) {
            int g = i * 1024 + t * 4;
            int e = g >> 6, u = g & 63;
            float4 hv = *(const float4*)(hN + E0 * 64 + g);
            hn[(u + 0) * 65 + e] = hv.x;
            hn[(u + 1) * 65 + e] = hv.y;
            hn[(u + 2) * 65 + e] = hv.z;
            hn[(u + 3) * 65 + e] = hv.w;
        }
        __syncthreads();
        {
            int d0 = wvu * 2;
            float m0 = b_mu[d0], m1 = b_mu[d0 + 1];
            float l0 = b_ls[d0], l1 = b_ls[d0 + 1];
#pragma unroll
            for (int u = 0; u < 64; ++u) {
                float hv = hn[u * 65 + lane];
                m0 = fmaf(hv, W_mu[u * 8 + d0],     m0);
                m1 = fmaf(hv, W_mu[u * 8 + d0 + 1], m1);
                l0 = fmaf(hv, W_ls[u * 8 + d0],     l0);
                l1 = fmaf(hv, W_ls[u * 8 + d0 + 1], l1);
            }
            int col = tile * 64 + lane;
            muls[(d0 + 0) * 257 + col] = m0;
            muls[(d0 + 1) * 257 + col] = m1;
            muls[(8 + d0 + 0) * 257 + col] = l0;
            muls[(8 + d0 + 1) * 257 + col] = l1;
        }
        __syncthreads();
    }

    const float* G6 = ws + G6_OFF;
    const float* G8 = ws + G8_OFF;
    const float* r6 = ws + R6_OFF;
    const float* r8 = ws + R8_OFF;
    const float  slr = ws[SLR_OFF];
    const size_t e = (size_t)blk * 256 + t;

    float mu[8], lsg[8];
#pragma unroll
    for (int d = 0; d < 8; ++d) {
        mu[d]  = muls[d * 257 + t];
        lsg[d] = muls[(8 + d) * 257 + t];
    }

    float sig[8], Sinv[8];
#pragma unroll
    for (int d = 0; d < 8; ++d) {
        float l = fminf(fmaxf(lsg[d], -5.0f), 3.0f);
        float s = __expf(l);
        sig[d]  = s;
        Sinv[d] = rcp1(s * s + 1e-8f);
    }

    float xv[16];
    {
        const float4* x4 = (const float4*)(x_in + e * 16);
#pragma unroll
        for (int q = 0; q < 4; ++q) {
            float4 v = x4[q];
            xv[4 * q + 0] = v.x; xv[4 * q + 1] = v.y;
            xv[4 * q + 2] = v.z; xv[4 * q + 3] = v.w;
        }
    }

    float t6[8], t8[8];
#pragma unroll
    for (int k = 0; k < 8; ++k) { t6[k] = 0.0f; t8[k] = 0.0f; }
    float qdr = 0.0f;
#pragma unroll
    for (int i = 0; i < 16; ++i) {
        float pm = b_em[i];
#pragma unroll
        for (int d = 0; d < 8; ++d) pm = fmaf(mu[d], Cm[i * 8 + d], pm);
        float df = xv[i] - pm;
        float xe = xv[i] - b_em[i];
        float a6 = df * r6[i];
        float a8 = xe * r8[i];
        qdr = fmaf(df, a6, qdr);
#pragma unroll
        for (int k = 0; k < 8; ++k) {
            t6[k] = fmaf(a6, Cm[i * 8 + k], t6[k]);
            t8[k] = fmaf(a8, Cm[i * 8 + k], t8[k]);
        }
    }

    // ---- alpha via Woodbury ----
    float M[8][8];
#pragma unroll
    for (int k = 0; k < 8; ++k)
#pragma unroll
        for (int l = 0; l <= k; ++l)
            M[k][l] = ((k == l) ? 1.0f : 0.0f) + sig[k] * sig[l] * G6[k * 8 + l];

    float ldia[8];
    float logdetM = 0.0f;
#pragma unroll
    for (int k = 0; k < 8; ++k) {
        float d = M[k][k];
#pragma unroll
        for (int j = 0; j < k; ++j) d = fmaf(-M[k][j], M[k][j], d);
        float l = sqrtf(d);
        logdetM += __logf(d);
        float li = rcp1(l);
        M[k][k] = l; ldia[k] = li;
#pragma unroll
        for (int i = k + 1; i < 8; ++i) {
            float s = M[i][k];
#pragma unroll
            for (int j = 0; j < k; ++j) s = fmaf(-M[i][j], M[k][j], s);
            M[i][k] = s * li;
        }
    }
    float w[8];
    float ssq = 0.0f;
#pragma unroll
    for (int k = 0; k < 8; ++k) {
        float s = sig[k] * t6[k];
#pragma unroll
        for (int j = 0; j < k; ++j) s = fmaf(-M[k][j], w[j], s);
        w[k] = s * ldia[k];
        ssq  = fmaf(w[k], w[k], ssq);
    }
    float mahal  = qdr - ssq;
    float logdet = slr + logdetM;
    float alpha  = -0.5f * (mahal + logdet + 29.40603306254952f); // 16*ln(2pi)

    // ---- gamma: V = (diag(Sinv)+1e-6 I + G8)^-1 ----
    float Vi[8][8];
#pragma unroll
    for (int k = 0; k < 8; ++k)
#pragma unroll
        for (int l = 0; l <= k; ++l)
            Vi[k][l] = G8[k * 8 + l] + ((k == l) ? (Sinv[k] + 1e-6f) : 0.0f);

    float vdia[8];
#pragma unroll
    for (int k = 0; k < 8; ++k) {
        float d = Vi[k][k];
#pragma unroll
        for (int j = 0; j < k; ++j) d = fmaf(-Vi[k][j], Vi[k][j], d);
        float l = sqrtf(d);
        float li = rcp1(l);
        Vi[k][k] = l; vdia[k] = li;
#pragma unroll
        for (int i = k + 1; i < 8; ++i) {
            float s = Vi[i][k];
#pragma unroll
            for (int j = 0; j < k; ++j) s = fmaf(-Vi[i][j], Vi[k][j], s);
            Vi[i][k] = s * li;
        }
    }
    // J = L^-1 (lower), stored into M (dead)
#pragma unroll
    for (int k = 0; k < 8; ++k) {
        M[k][k] = vdia[k];
#pragma unroll
        for (int i = k + 1; i < 8; ++i) {
            float s = 0.0f;
#pragma unroll
            for (int j = k; j < i; ++j) s = fmaf(Vi[i][j], M[j][k], s);
            M[i][k] = -s * vdia[i];
        }
    }
    float info[8];
#pragma unroll
    for (int k = 0; k < 8; ++k) info[k] = fmaf(Sinv[k], mu[k], t8[k]);

    // ---- V = J^T J + gamma, staged through LDS (reuse hn) in 4 chunks ----
    __syncthreads();
#pragma unroll 1
    for (int ch = 0; ch < 4; ++ch) {
        if (wv == ch) {
            float gam[8];
#pragma unroll
            for (int a = 0; a < 8; ++a) gam[a] = 0.0f;
#pragma unroll
            for (int a = 0; a < 8; ++a) {
#pragma unroll
                for (int b = 0; b < 8; ++b) {
                    int m0 = (a > b) ? a : b;
                    float s = 0.0f;
#pragma unroll
                    for (int i = 0; i < 8; ++i)
                        if (i >= m0) s = fmaf(M[i][a], M[i][b], s);
                    hn[(a * 8 + b) * 65 + lane] = s;
                    gam[a] = fmaf(s, info[b], gam[a]);
                }
            }
            out[e] = alpha;
            float4* outG = (float4*)(out + (size_t)BATCH + e * 8);
            outG[0] = make_float4(gam[0], gam[1], gam[2], gam[3]);
            outG[1] = make_float4(gam[4], gam[5], gam[6], gam[7]);
        }
        __syncthreads();
        {
            float* outV = out + (size_t)BATCH * 9 + ((size_t)blk * 256 + (size_t)ch * 64) * 64;
#pragma unroll
            for (int i = 0; i < 4; ++i) {
                int g = i * 1024 + t * 4;
                int ee = g >> 6, j = g & 63;
                float4 v = make_float4(hn[(j + 0) * 65 + ee], hn[(j + 1) * 65 + ee],
                                       hn[(j + 2) * 65 + ee], hn[(j + 3) * 65 + ee]);
                *(float4*)(outV + g) = v;
            }
        }
        __syncthreads();
    }
}

extern "C" void kernel_launch(void* const* d_in, const int* in_sizes, int n_in,
                              void* d_out, int out_size, void* d_ws, size_t ws_size,
                              hipStream_t stream) {
    const float* h    = (const float*)d_in[0];
    const float* c    = (const float*)d_in[1];
    const float* zp   = (const float*)d_in[2];
    const float* xt   = (const float*)d_in[3];
    const float* Wk   = (const float*)d_in[4];
    const float* Wr   = (const float*)d_in[5];
    const float* bl   = (const float*)d_in[6];
    const float* Wmu  = (const float*)d_in[7];
    const float* bmu  = (const float*)d_in[8];
    const float* Wls  = (const float*)d_in[9];
    const float* bls  = (const float*)d_in[10];
    const float* Cm   = (const float*)d_in[11];
    const float* bem  = (const float*)d_in[12];
    const float* logR = (const float*)d_in[13];
    float* ws  = (float*)d_ws;
    float* out = (float*)d_out;

    hipLaunchKernelGGL(prep_kernel, dim3(1), dim3(256), 0, stream, Wk, Wr, bl, Cm, logR, ws);
    hipLaunchKernelGGL(lstm_kernel, dim3(BATCH / 64), dim3(256), 0, stream,
                       h, c, zp, ws, out);
    hipLaunchKernelGGL(tail_kernel, dim3(BATCH / 256), dim3(256), 0, stream,
                       xt, Wmu, bmu, Wls, bls, Cm, bem, ws, out);
}